// Round 1
// 362.477 us; speedup vs baseline: 1.0611x; 1.0611x over previous
//
#include <hip/hip_runtime.h>

#define OUT_F 4096   // compressed rows
#define IN_F  2048   // compressed cols
#define KLOG  4096   // logical k = 2*IN_F
#define NB    4096   // batch
typedef unsigned long long ull;
typedef ull ullx2 __attribute__((ext_vector_type(2)));

typedef __bf16 bf16x8 __attribute__((ext_vector_type(8)));
typedef short  s16x8  __attribute__((ext_vector_type(8)));
typedef float  f32x4  __attribute__((ext_vector_type(4)));
typedef float  f32x16 __attribute__((ext_vector_type(16)));

__device__ __forceinline__ unsigned short f2bf(float f) {
    unsigned int u = __float_as_uint(f);
    u += 0x7fffu + ((u >> 16) & 1u);
    return (unsigned short)(u >> 16);
}

__device__ __forceinline__ void gload_lds16(const void* g, void* l) {
    __builtin_amdgcn_global_load_lds(
        (const __attribute__((address_space(1))) unsigned int*)g,
        (__attribute__((address_space(3))) unsigned int*)l, 16, 0, 0);
}

__device__ __forceinline__ bf16x8 ldsf(const char* p) {
    return __builtin_bit_cast(bf16x8, *(const s16x8*)p);
}

#define MFMA32(a, b, c) __builtin_amdgcn_mfma_f32_32x32x16_bf16((a), (b), (c), 0, 0, 0)

// ---------- Pre-pass: [0,4096) decompress weight -> bf16 wsA; [4096,8192) input -> bf16 wsB.
__global__ __launch_bounds__(256) void prep_kernel(
    const float* __restrict__ weight, const int* __restrict__ metadata,
    const float* __restrict__ input,
    unsigned short* __restrict__ wsA, unsigned short* __restrict__ wsB)
{
    const int b = blockIdx.x;
    if (b < 4096) {
        const int g = b * 256 + threadIdx.x;
        const int r = g >> 8;
        const int c = (g & 255) * 8;
        const size_t off = (size_t)r * IN_F + c;
        const float4 w0 = *(const float4*)(weight + off);
        const float4 w1 = *(const float4*)(weight + off + 4);
        const int4   m0 = *(const int4*)(metadata + off);
        const int4   m1 = *(const int4*)(metadata + off + 4);
        ullx2 v01, v23;
        v01.x = ((ull)f2bf(w0.x) << (m0.x * 16)) | ((ull)f2bf(w0.y) << (m0.y * 16));
        v01.y = ((ull)f2bf(w0.z) << (m0.z * 16)) | ((ull)f2bf(w0.w) << (m0.w * 16));
        v23.x = ((ull)f2bf(w1.x) << (m1.x * 16)) | ((ull)f2bf(w1.y) << (m1.y * 16));
        v23.y = ((ull)f2bf(w1.z) << (m1.z * 16)) | ((ull)f2bf(w1.w) << (m1.w * 16));
        ull* dst = (ull*)(wsA + (size_t)r * KLOG + 2 * c);
        *(ullx2*)(dst)     = v01;
        *(ullx2*)(dst + 2) = v23;
    } else {
        const int g = (b - 4096) * 256 + threadIdx.x;
        const size_t off = (size_t)g * 16;
        const float4 f0 = *(const float4*)(input + off);
        const float4 f1 = *(const float4*)(input + off + 4);
        const float4 f2 = *(const float4*)(input + off + 8);
        const float4 f3 = *(const float4*)(input + off + 12);
        ullx2 v01, v23;
        v01.x =  (ull)f2bf(f0.x) | ((ull)f2bf(f0.y) << 16) | ((ull)f2bf(f0.z) << 32) | ((ull)f2bf(f0.w) << 48);
        v01.y =  (ull)f2bf(f1.x) | ((ull)f2bf(f1.y) << 16) | ((ull)f2bf(f1.z) << 32) | ((ull)f2bf(f1.w) << 48);
        v23.x =  (ull)f2bf(f2.x) | ((ull)f2bf(f2.y) << 16) | ((ull)f2bf(f2.z) << 32) | ((ull)f2bf(f2.w) << 48);
        v23.y =  (ull)f2bf(f3.x) | ((ull)f2bf(f3.y) << 16) | ((ull)f2bf(f3.z) << 32) | ((ull)f2bf(f3.w) << 48);
        ull* dst = (ull*)(wsB + off);
        *(ullx2*)(dst)     = v01;
        *(ullx2*)(dst + 2) = v23;
    }
}

// ---------- Main GEMM: 256x256 tile, 8 waves (2M x 4N), BK=32, 32x32x16 bf16 MFMA.
// Ring-4 LDS buffers (128 KB), depth-3 prefetch, counted vmcnt(8) (never 0 in main loop),
// 2 barrier-phases per K-tile with setprio around MFMA clusters, XCD-aware tile swizzle.
// Swizzle: phys 16B-chunk = logical ^ ((row>>1)&3)  (carried over, conflict-free per 8-lane phase).
__global__ __launch_bounds__(512, 2) void gemm_kernel256(
    const unsigned short* __restrict__ wsA, const unsigned short* __restrict__ wsB,
    const int* __restrict__ indices, float* __restrict__ out)
{
    // 4 ring buffers x (A 256x32 bf16 = 16 KB, B 256x32 bf16 = 16 KB) = 128 KB
    __shared__ __align__(16) char lds[4 * 32768];

    const int tid  = threadIdx.x;
    const int lane = tid & 63;
    const int wave = tid >> 6;
    const int wm   = wave >> 2;   // 0..1 : 128-row half of the M-tile
    const int wn   = wave & 3;    // 0..3 : 64-col strip of the N-tile
    const int l31  = lane & 31;
    const int h    = lane >> 5;   // k-half of fragment

    // T1: XCD-aware swizzle. 256 blocks, 8 XCDs -> XCD x gets 32 consecutive tile ids
    // (= 2 full M-rows of tiles; A-panel 4 MB stays in that XCD's L2).
    const int swz = ((blockIdx.x & 7) << 5) | (blockIdx.x >> 3);
    const int r0 = (swz >> 4) << 8;   // M origin
    const int b0 = (swz & 15) << 8;   // N origin

    // ---- staging constants: one call covers 128 rows x 32 cols (8 KB), 16B/thread ----
    // LDS byte tid*16 -> row tid>>2, phys chunk tid&3 ; source logical chunk = phys ^ ((row>>1)&3)
    const int srow   = tid >> 2;                      // 0..127
    const int schunk = (tid & 3) ^ ((tid >> 3) & 3);  // pre-swizzled source 16B-chunk
    const unsigned short* gA = wsA + (size_t)(r0 + srow) * KLOG + schunk * 8;
    const unsigned short* gB = wsB + (size_t)(b0 + srow) * KLOG + schunk * 8;
    char* const ldsW = lds + wave * 1024;             // wave-uniform staging base

    // ---- fragment-read constants ----
    const int q = (l31 >> 1) & 3;                      // == (row>>1)&3 for all frag rows
    const unsigned x0 = (unsigned)(((0 + h) ^ q) * 16);  // k-step 0: logical chunks {0,1}
    const unsigned x1 = (unsigned)(((2 + h) ^ q) * 16);  // k-step 1: logical chunks {2,3}
    const unsigned aRow = (unsigned)((wm * 128 + l31) * 64);
    const unsigned bRow = (unsigned)((wn * 64  + l31) * 64);

    f32x16 acc[4][2];
#pragma unroll
    for (int i = 0; i < 4; ++i)
#pragma unroll
        for (int j = 0; j < 2; ++j)
#pragma unroll
            for (int e = 0; e < 16; ++e) acc[i][j][e] = 0.f;

#define STAGE_A(t_) do { \
        char* _d = ldsW + (((t_) & 3) * 32768); \
        const unsigned short* _s = gA + (t_) * 32; \
        gload_lds16(_s, _d); \
        gload_lds16(_s + (size_t)128 * KLOG, _d + 8192); } while (0)
#define STAGE_B(t_) do { \
        char* _d = ldsW + (((t_) & 3) * 32768) + 16384; \
        const unsigned short* _s = gB + (t_) * 32; \
        gload_lds16(_s, _d); \
        gload_lds16(_s + (size_t)128 * KLOG, _d + 8192); } while (0)

    // prologue: stage tiles 0,1,2 (12 loads/thread); wait oldest 4 (= tile 0)
    STAGE_A(0); STAGE_B(0);
    STAGE_A(1); STAGE_B(1);
    STAGE_A(2); STAGE_B(2);
    asm volatile("s_waitcnt vmcnt(8)" ::: "memory");
    __builtin_amdgcn_s_barrier();
    __builtin_amdgcn_sched_barrier(0);

    for (int t = 0; t < 128; ++t) {
        const unsigned bufA = (unsigned)(t & 3) * 32768u;
        const char* pA = lds + bufA + aRow;
        const char* pB = lds + bufA + 16384u + bRow;

        // ---------------- phase 0 (k-step 0) ----------------
        bf16x8 a0 = ldsf(pA + x0);
        bf16x8 a1 = ldsf(pA + 2048 + x0);
        bf16x8 a2 = ldsf(pA + 4096 + x0);
        bf16x8 a3 = ldsf(pA + 6144 + x0);
        bf16x8 bb0 = ldsf(pB + x0);
        bf16x8 bb1 = ldsf(pB + 2048 + x0);
        if (t < 125) STAGE_A(t + 3);
        __builtin_amdgcn_s_barrier();
        asm volatile("s_waitcnt lgkmcnt(0)" ::: "memory");
        __builtin_amdgcn_sched_barrier(0);
        __builtin_amdgcn_s_setprio(1);
        acc[0][0] = MFMA32(a0, bb0, acc[0][0]);
        acc[0][1] = MFMA32(a0, bb1, acc[0][1]);
        acc[1][0] = MFMA32(a1, bb0, acc[1][0]);
        acc[1][1] = MFMA32(a1, bb1, acc[1][1]);
        acc[2][0] = MFMA32(a2, bb0, acc[2][0]);
        acc[2][1] = MFMA32(a2, bb1, acc[2][1]);
        acc[3][0] = MFMA32(a3, bb0, acc[3][0]);
        acc[3][1] = MFMA32(a3, bb1, acc[3][1]);
        __builtin_amdgcn_s_setprio(0);
        __builtin_amdgcn_sched_barrier(0);

        // ---------------- phase 1 (k-step 1) ----------------
        a0 = ldsf(pA + x1);
        a1 = ldsf(pA + 2048 + x1);
        a2 = ldsf(pA + 4096 + x1);
        a3 = ldsf(pA + 6144 + x1);
        bb0 = ldsf(pB + x1);
        bb1 = ldsf(pB + 2048 + x1);
        if (t < 125) STAGE_B(t + 3);
        __builtin_amdgcn_s_barrier();
        asm volatile("s_waitcnt lgkmcnt(0)" ::: "memory");
        __builtin_amdgcn_sched_barrier(0);
        __builtin_amdgcn_s_setprio(1);
        acc[0][0] = MFMA32(a0, bb0, acc[0][0]);
        acc[0][1] = MFMA32(a0, bb1, acc[0][1]);
        acc[1][0] = MFMA32(a1, bb0, acc[1][0]);
        acc[1][1] = MFMA32(a1, bb1, acc[1][1]);
        acc[2][0] = MFMA32(a2, bb0, acc[2][0]);
        acc[3][0] = MFMA32(a3, bb0, acc[3][0]);
        acc[2][1] = MFMA32(a2, bb1, acc[2][1]);
        acc[3][1] = MFMA32(a3, bb1, acc[3][1]);
        __builtin_amdgcn_s_setprio(0);
        __builtin_amdgcn_sched_barrier(0);

        // ---------------- tile end: counted vmcnt (T4), never 0 until the tail ----------------
        if (t < 125) {
            asm volatile("s_waitcnt vmcnt(8)" ::: "memory");   // tiles t+2,t+3 stay in flight
        } else if (t == 125) {
            asm volatile("s_waitcnt vmcnt(4)" ::: "memory");   // tile 127 in flight
        } else if (t == 126) {
            asm volatile("s_waitcnt vmcnt(0)" ::: "memory");
        }
        __builtin_amdgcn_s_barrier();
        __builtin_amdgcn_sched_barrier(0);
    }
#undef STAGE_A
#undef STAGE_B

    // epilogue: C/D (32x32): col = l31, row = (reg&3) + 8*(reg>>2) + 4*h  [m74/m101]
#pragma unroll
    for (int fm = 0; fm < 4; ++fm) {
#pragma unroll
        for (int reg = 0; reg < 16; ++reg) {
            const int rloc = wm * 128 + fm * 32 + (reg & 3) + 8 * (reg >> 2) + 4 * h;
            const int L = indices[r0 + rloc];
            const size_t base  = (size_t)L * NB;
            const size_t baseZ = (size_t)(L ^ 1) * NB;
#pragma unroll
            for (int fn = 0; fn < 2; ++fn) {
                const int col = b0 + wn * 64 + fn * 32 + l31;
                out[base  + col] = acc[fm][fn][reg];
                out[baseZ + col] = 0.0f;
            }
        }
    }
}

// ---------- Fallback (round-1 fused kernel) if ws is too small ----------
__global__ __launch_bounds__(256) void spmm_dt_fallback(
    const float* __restrict__ weight, const int* __restrict__ indices,
    const int* __restrict__ metadata, const float* __restrict__ input,
    float* __restrict__ out)
{
    __shared__ __align__(16) unsigned short As[128][32];
    __shared__ __align__(16) unsigned short Bs[128][32];
    const int tid = threadIdx.x, lane = tid & 63, wave = tid >> 6;
    const int wm = wave >> 1, wn = wave & 1, l15 = lane & 15, quad = lane >> 4;
    const int r0 = blockIdx.y * 128, b0 = blockIdx.x * 128;
    f32x4 acc[4][4];
#pragma unroll
    for (int i = 0; i < 4; ++i)
#pragma unroll
        for (int j = 0; j < 4; ++j) acc[i][j] = (f32x4){0.f, 0.f, 0.f, 0.f};
    const int srow = tid >> 3, sgrp = tid & 7;
    for (int kk = 0; kk < KLOG / 32; ++kk) {
        const int c0 = kk * 16, k0 = kk * 32;
#pragma unroll
        for (int s = 0; s < 4; ++s) {
            const int row = srow + s * 32;
            const size_t off = (size_t)(r0 + row) * IN_F + c0 + 2 * sgrp;
            const float2 w = *(const float2*)(weight + off);
            const int2  md = *(const int2*)(metadata + off);
            *(ull*)(&As[row][4 * sgrp]) =
                ((ull)f2bf(w.x) << (md.x * 16)) | ((ull)f2bf(w.y) << (md.y * 16));
        }
#pragma unroll
        for (int s = 0; s < 4; ++s) {
            const int row = srow + s * 32;
            const float4 f = *(const float4*)(&input[(size_t)(b0 + row) * KLOG + k0 + sgrp * 4]);
            *(ull*)(&Bs[row][sgrp * 4]) =
                 (ull)f2bf(f.x) | ((ull)f2bf(f.y) << 16) |
                ((ull)f2bf(f.z) << 32) | ((ull)f2bf(f.w) << 48);
        }
        __syncthreads();
        bf16x8 a[4], b[4];
#pragma unroll
        for (int i = 0; i < 4; ++i)
            a[i] = __builtin_bit_cast(bf16x8, *(const s16x8*)(&As[wm * 64 + i * 16 + l15][quad * 8]));
#pragma unroll
        for (int j = 0; j < 4; ++j)
            b[j] = __builtin_bit_cast(bf16x8, *(const s16x8*)(&Bs[wn * 64 + j * 16 + l15][quad * 8]));
#pragma unroll
        for (int i = 0; i < 4; ++i)
#pragma unroll
            for (int j = 0; j < 4; ++j)
                acc[i][j] = __builtin_amdgcn_mfma_f32_16x16x32_bf16(a[i], b[j], acc[i][j], 0, 0, 0);
        __syncthreads();
    }
#pragma unroll
    for (int i = 0; i < 4; ++i)
#pragma unroll
        for (int t = 0; t < 4; ++t) {
            const int r = r0 + wm * 64 + i * 16 + quad * 4 + t;
            const int L = indices[r];
            const size_t base = (size_t)L * NB, baseZ = (size_t)(L ^ 1) * NB;
#pragma unroll
            for (int j = 0; j < 4; ++j) {
                const int col = b0 + wn * 64 + j * 16 + l15;
                out[base + col] = acc[i][j][t];
                out[baseZ + col] = 0.0f;
            }
        }
}

extern "C" void kernel_launch(void* const* d_in, const int* in_sizes, int n_in,
                              void* d_out, int out_size, void* d_ws, size_t ws_size,
                              hipStream_t stream) {
    const float* weight   = (const float*)d_in[0];
    const int*   indices  = (const int*)d_in[1];
    const int*   metadata = (const int*)d_in[2];
    const float* input    = (const float*)d_in[3];
    float*       out      = (float*)d_out;

    const size_t needA = (size_t)OUT_F * KLOG * 2;  // 32 MB
    const size_t needB = (size_t)NB * KLOG * 2;     // 32 MB
    if (ws_size >= needA + needB) {
        unsigned short* wsA = (unsigned short*)d_ws;
        unsigned short* wsB = wsA + (size_t)OUT_F * KLOG;
        prep_kernel<<<dim3(8192), dim3(256), 0, stream>>>(weight, metadata, input, wsA, wsB);
        gemm_kernel256<<<dim3(256), dim3(512), 0, stream>>>(wsA, wsB, indices, out);
    } else {
        spmm_dt_fallback<<<dim3(NB / 128, OUT_F / 128), dim3(256), 0, stream>>>(
            weight, indices, metadata, input, out);
    }
}